// Round 13
// baseline (558.643 us; speedup 1.0000x reference)
//
#include <hip/hip_runtime.h>

#define S_LEN 512
#define BATCH 256
#define EMB   300
#define HID   256
#define VOCAB 50257
#define NPROD 786
#define NLOG2E -1.44269504089f

#define EW_BYTES  25731584ull           // 50257*256*2 (f16, pre-scaled by -log2e)
#define AS_BYTES  67108864ull           // 512*256*256*2 (f16)

typedef __attribute__((ext_vector_type(8))) _Float16 f16x8;
typedef __attribute__((ext_vector_type(4))) _Float16 f16x4;
typedef __attribute__((ext_vector_type(2))) __fp16   fp16v2;
typedef __attribute__((ext_vector_type(4))) float    f32x4;

// Barrier waiting only lgkmcnt(0): LDS ordered, global loads stay in flight.
__device__ __forceinline__ void block_sync_lds() {
    asm volatile("" ::: "memory");
    __builtin_amdgcn_s_waitcnt(0xC07F);   // vmcnt=63, expcnt=7, lgkmcnt=0
    __builtin_amdgcn_s_barrier();
    asm volatile("" ::: "memory");
}

__device__ __forceinline__ float sigmoid_scaled(float xs) {   // xs = -log2e * x
    float e = __builtin_amdgcn_exp2f(xs);
    return __builtin_amdgcn_rcpf(1.0f + e);
}

// ---------------------------------------------------------------------------
// Stage 1: EW[v][j] = f16( -log2e * (emb[v] @ Wi)[j] ).  786 blocks x 64 rows.
// Block 0 also zeroes the 64 producer flags for stage 2.
// ---------------------------------------------------------------------------
__global__ __launch_bounds__(256, 1)
void k_embwi(const float* __restrict__ emb, const float* __restrict__ Wi,
             _Float16* __restrict__ EW, unsigned int* __restrict__ cnt) {
    const int tid  = threadIdx.x;
    if (blockIdx.x == 0 && tid < 64) cnt[tid] = 0u;

    const int wv   = tid >> 6;
    const int lane = tid & 63;
    const int ln   = lane & 15;
    const int q    = lane >> 4;
    const int m0   = blockIdx.x * 64;

    f16x8 bfrag[10][4];
#pragma unroll
    for (int kc = 0; kc < 10; kc++) {
#pragma unroll
        for (int nt = 0; nt < 4; nt++) {
            const int n = wv * 64 + nt * 16 + ln;
            f16x8 u;
#pragma unroll
            for (int j = 0; j < 8; j++) {
                const int k = kc * 32 + q * 8 + j;
                u[j] = (k < EMB) ? (_Float16)(Wi[k * HID + n] * NLOG2E) : (_Float16)0.f;
            }
            bfrag[kc][nt] = u;
        }
    }

    const float* arow[4];
#pragma unroll
    for (int mt = 0; mt < 4; mt++) {
        int row = m0 + mt * 16 + ln; if (row >= VOCAB) row = VOCAB - 1;
        arow[mt] = emb + (long)row * EMB + q * 8;
    }

    auto load_af = [&](int kc, int mt) -> f16x8 {
        const float* p = arow[mt] + kc * 32;
        f16x8 v;
        if (kc < 9 || q == 0) {
            f32x4 a = *(const f32x4*)p;
            f32x4 b = *(const f32x4*)(p + 4);
#pragma unroll
            for (int r = 0; r < 4; r++) { v[r] = (_Float16)a[r]; v[4 + r] = (_Float16)b[r]; }
        } else if (q == 1) {
            f32x4 a = *(const f32x4*)p;
#pragma unroll
            for (int r = 0; r < 4; r++) { v[r] = (_Float16)a[r]; v[4 + r] = (_Float16)0.f; }
        } else {
#pragma unroll
            for (int r = 0; r < 8; r++) v[r] = (_Float16)0.f;
        }
        return v;
    };

    f32x4 acc[4][4];
#pragma unroll
    for (int mt = 0; mt < 4; mt++)
#pragma unroll
        for (int nt = 0; nt < 4; nt++)
            acc[mt][nt] = f32x4{0.f, 0.f, 0.f, 0.f};

    f16x8 af[4], afn[4];
#pragma unroll
    for (int mt = 0; mt < 4; mt++) af[mt] = load_af(0, mt);

#pragma unroll
    for (int kc = 0; kc < 10; kc++) {
        if (kc < 9) {
#pragma unroll
            for (int mt = 0; mt < 4; mt++) afn[mt] = load_af(kc + 1, mt);
        }
#pragma unroll
        for (int mt = 0; mt < 4; mt++)
#pragma unroll
            for (int nt = 0; nt < 4; nt++)
                acc[mt][nt] = __builtin_amdgcn_mfma_f32_16x16x32_f16(
                    af[mt], bfrag[kc][nt], acc[mt][nt], 0, 0, 0);
#pragma unroll
        for (int mt = 0; mt < 4; mt++) af[mt] = afn[mt];
    }

#pragma unroll
    for (int mt = 0; mt < 4; mt++)
#pragma unroll
        for (int nt = 0; nt < 4; nt++) {
            const int col = wv * 64 + nt * 16 + ln;
#pragma unroll
            for (int r = 0; r < 4; r++) {
                const int mm = m0 + mt * 16 + q * 4 + r;
                if (mm < VOCAB) EW[(long)mm * HID + col] = (_Float16)acc[mt][nt][r];
            }
        }
}

// ---------------------------------------------------------------------------
// Stage 2 (fused): blocks 0-31 = recurrence consumers; blocks 32-159 =
// expand producers, 4 timesteps each. TOTAL GRID = 160 <= 256 CUs so
// breadth-first dispatch gives every block a private CU — R12's regression
// came from 544 blocks forcing producers co-resident on consumer CUs.
// ---------------------------------------------------------------------------
#define HSTR 264
#define HB8  (8 * HSTR)

__device__ void producer_body(int p, const int* __restrict__ words,
                              const _Float16* __restrict__ EW,
                              _Float16* __restrict__ As,
                              unsigned int* __restrict__ cnt) {
    const int tid = threadIdx.x;
    for (int tt = 0; tt < 4; tt++) {
        const int t = p * 4 + tt;
        _Float16* dst = As + (long)t * 65536;
        // 512 threads x 16 iters x 8 f16: 32-thread groups copy one 512 B row.
        for (int i = tid; i < 8192; i += 512) {
            const int e  = i << 3;
            const int b  = e >> 8;
            const int j0 = e & 255;
            const _Float16* src = EW + ((long)words[b * S_LEN + t] << 8) + j0;
            *(f16x8*)(dst + e) = *(const f16x8*)src;
        }
        __syncthreads();                   // drains vmcnt(0): stores for t done
        if (tid == 0) {
            __threadfence();               // agent-scope release
            __hip_atomic_fetch_add(&cnt[t >> 3], 1u,
                                   __ATOMIC_RELEASE, __HIP_MEMORY_SCOPE_AGENT);
        }
    }
}

__device__ __forceinline__ void wait_group(unsigned int* cnt, int g) {
    while (__hip_atomic_load(&cnt[g], __ATOMIC_ACQUIRE, __HIP_MEMORY_SCOPE_AGENT) < 8u)
        __builtin_amdgcn_s_sleep(2);
}

__device__ void consumer_body(const float* __restrict__ Wh, const _Float16* __restrict__ As,
                              const float* __restrict__ fcw, const float* __restrict__ fcb,
                              float* __restrict__ out, unsigned int* __restrict__ cnt) {
    __shared__ __attribute__((aligned(16))) _Float16 hbuf[2 * HB8];
    __shared__ float red[512];

    const int tid  = threadIdx.x;
    const int wv   = tid >> 6;        // 0..7, j-slice of 32
    const int lane = tid & 63;
    const int ln   = lane & 15;
    const int lnn  = ln & 7;          // broadcast source row (R10 dup-read scheme)
    const int q    = lane >> 4;
    const int b0   = blockIdx.x * 8;

    f16x8 whf[8][2];
#pragma unroll
    for (int kc = 0; kc < 8; kc++) {
#pragma unroll
        for (int mt = 0; mt < 2; mt++) {
            const int j = wv * 32 + mt * 16 + ln;
            f16x8 u;
#pragma unroll
            for (int jj = 0; jj < 8; jj++)
                u[jj] = (_Float16)(Wh[(kc * 32 + q * 8 + jj) * HID + j] * NLOG2E);
            whf[kc][mt] = u;
        }
    }

    for (int i = tid; i < 2 * HB8; i += 512) hbuf[i] = (_Float16)0.f;
    __syncthreads();

    wait_group(cnt, 0);                // covers initial prefetch t=0,1

    const int jbase = wv * 32 + q * 4;
    const _Float16* abase = As + (long)(b0 + lnn) * HID + jbase;
    f16x4 abuf0[2], abuf1[2];
#pragma unroll
    for (int mt = 0; mt < 2; mt++) abuf0[mt] = *(const f16x4*)(abase + 0L * 65536 + mt * 16);
#pragma unroll
    for (int mt = 0; mt < 2; mt++) abuf1[mt] = *(const f16x4*)(abase + 1L * 65536 + mt * 16);

#define STEP(T, ABUF)                                                                   \
    {                                                                                   \
        const int tt = (T);                                                             \
        const _Float16* hr = hbuf + ((tt & 1) ? HB8 : 0);                               \
        _Float16*       hw = hbuf + ((tt & 1) ? 0 : HB8);                               \
        f16x8 hf[8];                                                                    \
        _Pragma("unroll")                                                               \
        for (int kc = 0; kc < 8; kc++)                                                  \
            hf[kc] = *(const f16x8*)(hr + lnn * HSTR + kc * 32 + q * 8);                \
        f32x4 acc_a[2], acc_b[2];                                                       \
        _Pragma("unroll")                                                               \
        for (int mt = 0; mt < 2; mt++) {                                                \
            f16x4 av = ABUF[mt];                                                        \
            acc_a[mt] = f32x4{(float)av[0], (float)av[1], (float)av[2], (float)av[3]};  \
            acc_b[mt] = f32x4{0.f, 0.f, 0.f, 0.f};                                      \
        }                                                                               \
        const long t2 = (tt + 2 > 511) ? 511 : (tt + 2);                                \
        const _Float16* rp = abase + t2 * 65536;                                        \
        _Pragma("unroll")                                                               \
        for (int mt = 0; mt < 2; mt++) ABUF[mt] = *(const f16x4*)(rp + mt * 16);        \
        _Pragma("unroll")                                                               \
        for (int r = 0; r < 4; r++) {                                                   \
            _Pragma("unroll")                                                           \
            for (int mt = 0; mt < 2; mt++)                                              \
                acc_a[mt] = __builtin_amdgcn_mfma_f32_16x16x32_f16(                     \
                    whf[r][mt], hf[r], acc_a[mt], 0, 0, 0);                             \
            _Pragma("unroll")                                                           \
            for (int mt = 0; mt < 2; mt++)                                              \
                acc_b[mt] = __builtin_amdgcn_mfma_f32_16x16x32_f16(                     \
                    whf[r + 4][mt], hf[r + 4], acc_b[mt], 0, 0, 0);                     \
        }                                                                               \
        _Pragma("unroll")                                                               \
        for (int mt = 0; mt < 2; mt++) {                                                \
            f32x4 s = acc_a[mt] + acc_b[mt];                                            \
            float r0 = sigmoid_scaled(s[0]), r1 = sigmoid_scaled(s[1]);                 \
            float r2 = sigmoid_scaled(s[2]), r3 = sigmoid_scaled(s[3]);                 \
            union { fp16v2 h2[2]; f16x4 v4; } hp;                                       \
            hp.h2[0] = __builtin_amdgcn_cvt_pkrtz(r0, r1);                              \
            hp.h2[1] = __builtin_amdgcn_cvt_pkrtz(r2, r3);                              \
            if (ln < 8)                                                                 \
                *(f16x4*)(hw + ln * HSTR + wv * 32 + mt * 16 + q * 4) = hp.v4;          \
        }                                                                               \
        block_sync_lds();                                                               \
    }

    for (int g = 0; g < 64; g++) {
        wait_group(cnt, (g + 1 > 63) ? 63 : g + 1);   // covers prefetch t<=8g+9
        const int t0 = g * 8;
#pragma unroll
        for (int u = 0; u < 8; u += 2) {
            STEP(t0 + u,     abuf0);
            STEP(t0 + u + 1, abuf1);
        }
    }
#undef STEP

    const _Float16* hf0 = hbuf;   // step 511 (odd) wrote buffer 0

    {   // hidden -> out[256 + (b0+row)*256 + j], rows 0..7, 4 f32 per thread
        const int row = tid >> 6, j0 = (tid & 63) * 4;
        float* dst = out + 256 + (long)(b0 + row) * HID + j0;
        f32x4 w;
#pragma unroll
        for (int r = 0; r < 4; r++) w[r] = (float)hf0[row * HSTR + j0 + r];
        *(f32x4*)dst = w;
    }

    {   // sig head: 64 partials x 4 elems per row
        const int row = tid >> 6, part = tid & 63;
        float s = 0.f;
#pragma unroll
        for (int jj = 0; jj < 4; jj++) {
            const int j = part * 4 + jj;
            s += (float)hf0[row * HSTR + j] * fcw[j];
        }
        red[row * 64 + part] = s;
    }
    __syncthreads();
    if (tid < 8) {
        float s = fcb[0];
#pragma unroll
        for (int p = 0; p < 64; p++) s += red[tid * 64 + p];
        s *= NLOG2E;
        out[b0 + tid] = sigmoid_scaled(s);
    }
}

__global__ __launch_bounds__(512, 2)
void k_fused(const int* __restrict__ words, const _Float16* __restrict__ EW,
             const float* __restrict__ Wh, _Float16* __restrict__ As,
             const float* __restrict__ fcw, const float* __restrict__ fcb,
             unsigned int* __restrict__ cnt, float* __restrict__ out) {
    if (blockIdx.x < 32) consumer_body(Wh, As, fcw, fcb, out, cnt);
    else                 producer_body(blockIdx.x - 32, words, EW, As, cnt);
}

extern "C" void kernel_launch(void* const* d_in, const int* in_sizes, int n_in,
                              void* d_out, int out_size, void* d_ws, size_t ws_size,
                              hipStream_t stream) {
    const int*   words = (const int*)d_in[0];
    const float* emb   = (const float*)d_in[1];
    const float* Wi    = (const float*)d_in[2];
    const float* Wh    = (const float*)d_in[3];
    const float* fcw   = (const float*)d_in[4];
    const float* fcb   = (const float*)d_in[5];
    _Float16*     EW   = (_Float16*)d_ws;                              // 25.7 MB
    _Float16*     As   = (_Float16*)((char*)d_ws + EW_BYTES);          // 64 MB
    unsigned int* cnt  = (unsigned int*)((char*)d_ws + EW_BYTES + AS_BYTES);
    float*        outp = (float*)d_out;

    hipLaunchKernelGGL(k_embwi, dim3(NPROD), dim3(256), 0, stream, emb, Wi, EW, cnt);
    hipLaunchKernelGGL(k_fused, dim3(32 + 128), dim3(512), 0, stream,
                       words, EW, Wh, As, fcw, fcb, cnt, outp);
}

// Round 14
// 456.552 us; speedup vs baseline: 1.2236x; 1.2236x over previous
//
#include <hip/hip_runtime.h>

#define S_LEN 512
#define BATCH 256
#define EMB   300
#define HID   256
#define VOCAB 50257
#define NPROD 786
#define NLOG2E -1.44269504089f

#define EW_BYTES 25731584ull            // 50257*256*2 (f16, pre-scaled by -log2e)

typedef __attribute__((ext_vector_type(8))) _Float16 f16x8;
typedef __attribute__((ext_vector_type(4))) _Float16 f16x4;
typedef __attribute__((ext_vector_type(2))) __fp16   fp16v2;
typedef __attribute__((ext_vector_type(4))) float    f32x4;

// Barrier waiting only lgkmcnt(0): LDS ordered, global loads stay in flight.
__device__ __forceinline__ void block_sync_lds() {
    asm volatile("" ::: "memory");
    __builtin_amdgcn_s_waitcnt(0xC07F);   // vmcnt=63, expcnt=7, lgkmcnt=0
    __builtin_amdgcn_s_barrier();
    asm volatile("" ::: "memory");
}

__device__ __forceinline__ float sigmoid_scaled(float xs) {   // xs = -log2e * x
    float e = __builtin_amdgcn_exp2f(xs);
    return __builtin_amdgcn_rcpf(1.0f + e);
}

// ---------------------------------------------------------------------------
// Stage 1: EW[v][j] = f16( -log2e * (emb[v] @ Wi)[j] ).  786 blocks x 64 rows.
// (R9/R10 version — measured best; 197x4 multi-tile regressed in R11.)
// ---------------------------------------------------------------------------
__global__ __launch_bounds__(256, 1)
void k_embwi(const float* __restrict__ emb, const float* __restrict__ Wi,
             _Float16* __restrict__ EW) {
    const int tid  = threadIdx.x;
    const int wv   = tid >> 6;
    const int lane = tid & 63;
    const int ln   = lane & 15;
    const int q    = lane >> 4;
    const int m0   = blockIdx.x * 64;

    f16x8 bfrag[10][4];
#pragma unroll
    for (int kc = 0; kc < 10; kc++) {
#pragma unroll
        for (int nt = 0; nt < 4; nt++) {
            const int n = wv * 64 + nt * 16 + ln;
            f16x8 u;
#pragma unroll
            for (int j = 0; j < 8; j++) {
                const int k = kc * 32 + q * 8 + j;
                u[j] = (k < EMB) ? (_Float16)(Wi[k * HID + n] * NLOG2E) : (_Float16)0.f;
            }
            bfrag[kc][nt] = u;
        }
    }

    const float* arow[4];
#pragma unroll
    for (int mt = 0; mt < 4; mt++) {
        int row = m0 + mt * 16 + ln; if (row >= VOCAB) row = VOCAB - 1;
        arow[mt] = emb + (long)row * EMB + q * 8;
    }

    auto load_af = [&](int kc, int mt) -> f16x8 {
        const float* p = arow[mt] + kc * 32;
        f16x8 v;
        if (kc < 9 || q == 0) {
            f32x4 a = *(const f32x4*)p;
            f32x4 b = *(const f32x4*)(p + 4);
#pragma unroll
            for (int r = 0; r < 4; r++) { v[r] = (_Float16)a[r]; v[4 + r] = (_Float16)b[r]; }
        } else if (q == 1) {
            f32x4 a = *(const f32x4*)p;
#pragma unroll
            for (int r = 0; r < 4; r++) { v[r] = (_Float16)a[r]; v[4 + r] = (_Float16)0.f; }
        } else {
#pragma unroll
            for (int r = 0; r < 8; r++) v[r] = (_Float16)0.f;
        }
        return v;
    };

    f32x4 acc[4][4];
#pragma unroll
    for (int mt = 0; mt < 4; mt++)
#pragma unroll
        for (int nt = 0; nt < 4; nt++)
            acc[mt][nt] = f32x4{0.f, 0.f, 0.f, 0.f};

    f16x8 af[4], afn[4];
#pragma unroll
    for (int mt = 0; mt < 4; mt++) af[mt] = load_af(0, mt);

#pragma unroll
    for (int kc = 0; kc < 10; kc++) {
        if (kc < 9) {
#pragma unroll
            for (int mt = 0; mt < 4; mt++) afn[mt] = load_af(kc + 1, mt);
        }
#pragma unroll
        for (int mt = 0; mt < 4; mt++)
#pragma unroll
            for (int nt = 0; nt < 4; nt++)
                acc[mt][nt] = __builtin_amdgcn_mfma_f32_16x16x32_f16(
                    af[mt], bfrag[kc][nt], acc[mt][nt], 0, 0, 0);
#pragma unroll
        for (int mt = 0; mt < 4; mt++) af[mt] = afn[mt];
    }

#pragma unroll
    for (int mt = 0; mt < 4; mt++)
#pragma unroll
        for (int nt = 0; nt < 4; nt++) {
            const int col = wv * 64 + nt * 16 + ln;
#pragma unroll
            for (int r = 0; r < 4; r++) {
                const int mm = m0 + mt * 16 + q * 4 + r;
                if (mm < VOCAB) EW[(long)mm * HID + col] = (_Float16)acc[mt][nt][r];
            }
        }
}

// ---------------------------------------------------------------------------
// Stage 2: A_seq[t][b][j] = EW[words[b,t]][j]  (serial full-GPU expand —
// fusing this under the recurrence regressed in R12 (+87µs) and R13 (+132µs)).
// ---------------------------------------------------------------------------
__global__ __launch_bounds__(256)
void k_expand(const int* __restrict__ words, const _Float16* __restrict__ EW,
              _Float16* __restrict__ As) {
    const int g  = blockIdx.x * 256 + threadIdx.x;
    const int e0 = g << 3;
    const int t  = e0 >> 16;
    const int b  = (e0 >> 8) & 255;
    const int j0 = e0 & 255;
    const _Float16* src = EW + ((long)words[b * S_LEN + t] << 8) + j0;
    *(f16x8*)(As + e0) = *(const f16x8*)src;
}

// ---------------------------------------------------------------------------
// Stage 3: recurrence. 32 blocks x 8 batch rows, 512 threads (8 waves,
// 2/SIMD — sibling wave fills dependency stalls). Measured optimum of the
// family: 16 rows/block=334µs (R9), exec-masked reads=295µs (R11), this=287µs.
// Lanes ln>=8 duplicate-read lanes ln-8 (outputs cols 8-15 never stored);
// writes predicated ln<8. One lgkm-only barrier/step; depth-2 A prefetch;
// dual independent MFMA chains; -log2e folded into weights; pkrtz packing.
// ---------------------------------------------------------------------------
#define HSTR 264
#define HB8  (8 * HSTR)

__global__ __launch_bounds__(512, 2)
void k_recur(const float* __restrict__ Wh, const _Float16* __restrict__ As,
             const float* __restrict__ fcw, const float* __restrict__ fcb,
             float* __restrict__ out) {
    __shared__ __attribute__((aligned(16))) _Float16 hbuf[2 * HB8];
    __shared__ float red[512];

    const int tid  = threadIdx.x;
    const int wv   = tid >> 6;        // 0..7, j-slice of 32
    const int lane = tid & 63;
    const int ln   = lane & 15;
    const int lnn  = ln & 7;          // broadcast source row
    const int q    = lane >> 4;
    const int b0   = blockIdx.x * 8;

    f16x8 whf[8][2];
#pragma unroll
    for (int kc = 0; kc < 8; kc++) {
#pragma unroll
        for (int mt = 0; mt < 2; mt++) {
            const int j = wv * 32 + mt * 16 + ln;
            f16x8 u;
#pragma unroll
            for (int jj = 0; jj < 8; jj++)
                u[jj] = (_Float16)(Wh[(kc * 32 + q * 8 + jj) * HID + j] * NLOG2E);
            whf[kc][mt] = u;
        }
    }

    for (int i = tid; i < 2 * HB8; i += 512) hbuf[i] = (_Float16)0.f;
    __syncthreads();

    const int jbase = wv * 32 + q * 4;
    const _Float16* abase = As + (long)(b0 + lnn) * HID + jbase;
    f16x4 abuf0[2], abuf1[2];
#pragma unroll
    for (int mt = 0; mt < 2; mt++) abuf0[mt] = *(const f16x4*)(abase + 0L * 65536 + mt * 16);
#pragma unroll
    for (int mt = 0; mt < 2; mt++) abuf1[mt] = *(const f16x4*)(abase + 1L * 65536 + mt * 16);

#define STEP(T, ABUF)                                                                   \
    {                                                                                   \
        const int tt = (T);                                                             \
        const _Float16* hr = hbuf + ((tt & 1) ? HB8 : 0);                               \
        _Float16*       hw = hbuf + ((tt & 1) ? 0 : HB8);                               \
        f16x8 hf[8];                                                                    \
        _Pragma("unroll")                                                               \
        for (int kc = 0; kc < 8; kc++)                                                  \
            hf[kc] = *(const f16x8*)(hr + lnn * HSTR + kc * 32 + q * 8);                \
        f32x4 acc_a[2], acc_b[2];                                                       \
        _Pragma("unroll")                                                               \
        for (int mt = 0; mt < 2; mt++) {                                                \
            f16x4 av = ABUF[mt];                                                        \
            acc_a[mt] = f32x4{(float)av[0], (float)av[1], (float)av[2], (float)av[3]};  \
            acc_b[mt] = f32x4{0.f, 0.f, 0.f, 0.f};                                      \
        }                                                                               \
        const long t2 = (tt + 2 > 511) ? 511 : (tt + 2);                                \
        const _Float16* rp = abase + t2 * 65536;                                        \
        _Pragma("unroll")                                                               \
        for (int mt = 0; mt < 2; mt++) ABUF[mt] = *(const f16x4*)(rp + mt * 16);        \
        _Pragma("unroll")                                                               \
        for (int r = 0; r < 4; r++) {                                                   \
            _Pragma("unroll")                                                           \
            for (int mt = 0; mt < 2; mt++)                                              \
                acc_a[mt] = __builtin_amdgcn_mfma_f32_16x16x32_f16(                     \
                    whf[r][mt], hf[r], acc_a[mt], 0, 0, 0);                             \
            _Pragma("unroll")                                                           \
            for (int mt = 0; mt < 2; mt++)                                              \
                acc_b[mt] = __builtin_amdgcn_mfma_f32_16x16x32_f16(                     \
                    whf[r + 4][mt], hf[r + 4], acc_b[mt], 0, 0, 0);                     \
        }                                                                               \
        _Pragma("unroll")                                                               \
        for (int mt = 0; mt < 2; mt++) {                                                \
            f32x4 s = acc_a[mt] + acc_b[mt];                                            \
            float r0 = sigmoid_scaled(s[0]), r1 = sigmoid_scaled(s[1]);                 \
            float r2 = sigmoid_scaled(s[2]), r3 = sigmoid_scaled(s[3]);                 \
            union { fp16v2 h2[2]; f16x4 v4; } hp;                                       \
            hp.h2[0] = __builtin_amdgcn_cvt_pkrtz(r0, r1);                              \
            hp.h2[1] = __builtin_amdgcn_cvt_pkrtz(r2, r3);                              \
            if (ln < 8)                                                                 \
                *(f16x4*)(hw + ln * HSTR + wv * 32 + mt * 16 + q * 4) = hp.v4;          \
        }                                                                               \
        block_sync_lds();                                                               \
    }

    for (int t = 0; t < S_LEN; t += 2) {
        STEP(t, abuf0);
        STEP(t + 1, abuf1);
    }
#undef STEP

    const _Float16* hf0 = hbuf;   // step 511 (odd) wrote buffer 0

    {   // hidden -> out[256 + (b0+row)*256 + j], rows 0..7, 4 f32 per thread
        const int row = tid >> 6, j0 = (tid & 63) * 4;
        float* dst = out + 256 + (long)(b0 + row) * HID + j0;
        f32x4 w;
#pragma unroll
        for (int r = 0; r < 4; r++) w[r] = (float)hf0[row * HSTR + j0 + r];
        *(f32x4*)dst = w;
    }

    {   // sig head: 64 partials x 4 elems per row
        const int row = tid >> 6, part = tid & 63;
        float s = 0.f;
#pragma unroll
        for (int jj = 0; jj < 4; jj++) {
            const int j = part * 4 + jj;
            s += (float)hf0[row * HSTR + j] * fcw[j];
        }
        red[row * 64 + part] = s;
    }
    __syncthreads();
    if (tid < 8) {
        float s = fcb[0];
#pragma unroll
        for (int p = 0; p < 64; p++) s += red[tid * 64 + p];
        s *= NLOG2E;
        out[b0 + tid] = sigmoid_scaled(s);
    }
}

extern "C" void kernel_launch(void* const* d_in, const int* in_sizes, int n_in,
                              void* d_out, int out_size, void* d_ws, size_t ws_size,
                              hipStream_t stream) {
    const int*   words = (const int*)d_in[0];
    const float* emb   = (const float*)d_in[1];
    const float* Wi    = (const float*)d_in[2];
    const float* Wh    = (const float*)d_in[3];
    const float* fcw   = (const float*)d_in[4];
    const float* fcb   = (const float*)d_in[5];
    _Float16* EW   = (_Float16*)d_ws;                          // 25.7 MB f16
    _Float16* As   = (_Float16*)((char*)d_ws + EW_BYTES);      // 64 MB f16
    float*    outp = (float*)d_out;

    hipLaunchKernelGGL(k_embwi,  dim3(NPROD), dim3(256), 0, stream, emb, Wi, EW);
    hipLaunchKernelGGL(k_expand, dim3(16384), dim3(256), 0, stream, words, EW, As);
    hipLaunchKernelGGL(k_recur,  dim3(BATCH / 8), dim3(512), 0, stream,
                       Wh, As, fcw, fcb, outp);
}